// Round 1
// baseline (813.818 us; speedup 1.0000x reference)
//
#include <hip/hip_runtime.h>
#include <hip/hip_bf16.h>

#define NB_ 16      // batches
#define LA_ 1024
#define LB_ 1024
#define H_  512

using bf16 = __hip_bfloat16;

// ---------------------------------------------------------------------------
// K1: S = a . b^T * temp ; E = mask ? exp(S) : 0  (stored bf16)
// 64x64 tile per block, BK=16, fp32, 4x4 outputs/thread
// ---------------------------------------------------------------------------
__global__ __launch_bounds__(256) void k_attn_exp(
    const float* __restrict__ a, const float* __restrict__ b,
    const int* __restrict__ mask_a, const int* __restrict__ mask_b,
    const float* __restrict__ temp_p, bf16* __restrict__ E)
{
    const int batch = blockIdx.z;
    const int i0 = blockIdx.y * 64, j0 = blockIdx.x * 64;
    const float temp = temp_p[0];
    __shared__ float As[16][64], Bs[16][64];
    const float* ap = a + (size_t)batch * LA_ * H_;
    const float* bp = b + (size_t)batch * LB_ * H_;
    const int t  = threadIdx.x;
    const int lr = t >> 2;            // 0..63 tile row for staging
    const int lk = (t & 3) * 4;       // 0,4,8,12 k offset for staging
    const int ty = t >> 4, tx = t & 15;
    float acc[4][4] = {};

    for (int k0 = 0; k0 < H_; k0 += 16) {
        float4 av = *(const float4*)(ap + (size_t)(i0 + lr) * H_ + k0 + lk);
        float4 bv = *(const float4*)(bp + (size_t)(j0 + lr) * H_ + k0 + lk);
        __syncthreads();
        As[lk + 0][lr] = av.x; As[lk + 1][lr] = av.y; As[lk + 2][lr] = av.z; As[lk + 3][lr] = av.w;
        Bs[lk + 0][lr] = bv.x; Bs[lk + 1][lr] = bv.y; Bs[lk + 2][lr] = bv.z; Bs[lk + 3][lr] = bv.w;
        __syncthreads();
#pragma unroll
        for (int k = 0; k < 16; k++) {
            float4 am = *(const float4*)&As[k][ty * 4];
            float4 bn = *(const float4*)&Bs[k][tx * 4];
            float amv[4] = {am.x, am.y, am.z, am.w};
            float bnv[4] = {bn.x, bn.y, bn.z, bn.w};
#pragma unroll
            for (int u = 0; u < 4; u++)
#pragma unroll
                for (int v = 0; v < 4; v++) acc[u][v] += amv[u] * bnv[v];
        }
    }

    const int* map = mask_a + batch * LA_;
    const int* mbp = mask_b + batch * LB_;
    bf16* Ep = E + (size_t)batch * LA_ * LB_;
#pragma unroll
    for (int u = 0; u < 4; u++) {
        const int i = i0 + ty * 4 + u;
        const int ma = map[i];
        unsigned short pack[4];
#pragma unroll
        for (int v = 0; v < 4; v++) {
            const int j = j0 + tx * 4 + v;
            float e = (ma && mbp[j]) ? expf(acc[u][v] * temp) : 0.0f;
            bf16 h = __float2bfloat16(e);
            pack[v] = *(unsigned short*)&h;
        }
        *(ushort4*)((unsigned short*)Ep + (size_t)i * LB_ + j0 + tx * 4) =
            make_ushort4(pack[0], pack[1], pack[2], pack[3]);
    }
}

// ---------------------------------------------------------------------------
// row sums: one wave per row of E (flat over B*LA rows)
// ---------------------------------------------------------------------------
__global__ __launch_bounds__(256) void k_rowsum(const bf16* __restrict__ E,
                                                float* __restrict__ l_row)
{
    const int w = threadIdx.x >> 6, lane = threadIdx.x & 63;
    const int row = blockIdx.x * 4 + w;
    const bf16* Ep = E + (size_t)row * LB_;
    float s = 0.0f;
    for (int j = lane; j < LB_; j += 64) s += __bfloat162float(Ep[j]);
    for (int off = 32; off; off >>= 1) s += __shfl_down(s, off, 64);
    if (lane == 0) l_row[row] = s;
}

// ---------------------------------------------------------------------------
// col sums: block = (batch, 64-col chunk), 4 row-slices x 64 cols
// ---------------------------------------------------------------------------
__global__ __launch_bounds__(256) void k_colsum(const bf16* __restrict__ E,
                                                float* __restrict__ l_col)
{
    const int batch = blockIdx.x >> 4, jc = blockIdx.x & 15;
    const int jl = threadIdx.x & 63;
    const int slice = threadIdx.x >> 6;
    const bf16* Ep = E + (size_t)batch * LA_ * LB_ + jc * 64 + jl;
    float s = 0.0f;
    for (int i = slice * 256; i < slice * 256 + 256; i++)
        s += __bfloat162float(Ep[(size_t)i * LB_]);
    __shared__ float part[4][64];
    part[slice][jl] = s;
    __syncthreads();
    if (threadIdx.x < 64) {
        float v = part[0][threadIdx.x] + part[1][threadIdx.x] +
                  part[2][threadIdx.x] + part[3][threadIdx.x];
        l_col[batch * LB_ + jc * 64 + threadIdx.x] = v;
    }
}

// ---------------------------------------------------------------------------
// per-batch column means of a and b (for fully-masked fallback)
// ---------------------------------------------------------------------------
__global__ __launch_bounds__(256) void k_mean(const float* __restrict__ a,
                                              const float* __restrict__ b,
                                              float* __restrict__ mean_a,
                                              float* __restrict__ mean_b)
{
    const int d = blockIdx.x * 256 + threadIdx.x;
    const int batch = blockIdx.y;
    const float* src = (blockIdx.z == 0) ? a : b;
    float* dst = (blockIdx.z == 0) ? mean_a : mean_b;
    const float* p = src + (size_t)batch * 1024 * H_ + d;
    float s = 0.0f;
    for (int i = 0; i < 1024; i++) s += p[(size_t)i * H_];
    dst[batch * H_ + d] = s * (1.0f / 1024.0f);
}

// ---------------------------------------------------------------------------
// mask token counts per batch
// ---------------------------------------------------------------------------
__global__ __launch_bounds__(256) void k_count(const int* __restrict__ mask_a,
                                               const int* __restrict__ mask_b,
                                               int* __restrict__ nA, int* __restrict__ nB)
{
    const int batch = blockIdx.x, t = threadIdx.x;
    int sa = 0, sb = 0;
    for (int i = t; i < 1024; i += 256) {
        sa += mask_a[batch * 1024 + i];
        sb += mask_b[batch * 1024 + i];
    }
    __shared__ int ra[256], rb[256];
    ra[t] = sa; rb[t] = sb;
    __syncthreads();
    for (int off = 128; off; off >>= 1) {
        if (t < off) { ra[t] += ra[t + off]; rb[t] += rb[t + off]; }
        __syncthreads();
    }
    if (t == 0) { nA[batch] = ra[0]; nB[batch] = rb[0]; }
}

// ---------------------------------------------------------------------------
// K2: feature_a[i,d] = (sum_j E[i,j] * b[j,d]) / l_row[i]   (or mean_b[d])
// ---------------------------------------------------------------------------
__global__ __launch_bounds__(256) void k_feat_a(
    const bf16* __restrict__ E, const float* __restrict__ b,
    const int* __restrict__ mask_a, const int* __restrict__ nB,
    const float* __restrict__ l_row, const float* __restrict__ mean_b,
    float* __restrict__ out)
{
    const int batch = blockIdx.z;
    const int i0 = blockIdx.y * 64, d0 = blockIdx.x * 64;
    __shared__ float Es[16][64], Bs[16][64];
    const unsigned short* Ep = (const unsigned short*)E + (size_t)batch * LA_ * LB_;
    const float* bp = b + (size_t)batch * LB_ * H_;
    const int t  = threadIdx.x;
    const int er = t >> 2,  ek = (t & 3) * 4;   // E staging: row (i), k offs (j)
    const int br = t >> 4,  bc = (t & 15) * 4;  // b staging: row (j=k), col (d)
    const int ty = t >> 4, tx = t & 15;
    float acc[4][4] = {};

    for (int k0 = 0; k0 < LB_; k0 += 16) {
        ushort4 ev = *(const ushort4*)(Ep + (size_t)(i0 + er) * LB_ + k0 + ek);
        float4  bv = *(const float4*)(bp + (size_t)(k0 + br) * H_ + d0 + bc);
        __syncthreads();
        Es[ek + 0][er] = __bfloat162float(*(bf16*)&ev.x);
        Es[ek + 1][er] = __bfloat162float(*(bf16*)&ev.y);
        Es[ek + 2][er] = __bfloat162float(*(bf16*)&ev.z);
        Es[ek + 3][er] = __bfloat162float(*(bf16*)&ev.w);
        *(float4*)&Bs[br][bc] = bv;
        __syncthreads();
#pragma unroll
        for (int k = 0; k < 16; k++) {
            float4 am = *(const float4*)&Es[k][ty * 4];
            float4 bn = *(const float4*)&Bs[k][tx * 4];
            float amv[4] = {am.x, am.y, am.z, am.w};
            float bnv[4] = {bn.x, bn.y, bn.z, bn.w};
#pragma unroll
            for (int u = 0; u < 4; u++)
#pragma unroll
                for (int v = 0; v < 4; v++) acc[u][v] += amv[u] * bnv[v];
        }
    }

    const int nb = nB[batch];
#pragma unroll
    for (int u = 0; u < 4; u++) {
        const int i = i0 + ty * 4 + u;
        const int valid = mask_a[batch * LA_ + i] && (nb > 0);
        const float inv = valid ? 1.0f / l_row[batch * LA_ + i] : 0.0f;
#pragma unroll
        for (int v = 0; v < 4; v++) {
            const int d = d0 + tx * 4 + v;
            float val = valid ? acc[u][v] * inv : mean_b[batch * H_ + d];
            out[(size_t)batch * LA_ * H_ + (size_t)i * H_ + d] = val;
        }
    }
}

// ---------------------------------------------------------------------------
// K3: feature_b[j,d] = (sum_i E[i,j] * a[i,d]) / l_col[j]   (or mean_a[d])
// E^T's [j][i] tile == E row-major tile, no transpose needed in staging.
// ---------------------------------------------------------------------------
__global__ __launch_bounds__(256) void k_feat_b(
    const bf16* __restrict__ E, const float* __restrict__ a,
    const int* __restrict__ mask_b, const int* __restrict__ nA,
    const float* __restrict__ l_col, const float* __restrict__ mean_a,
    float* __restrict__ out)
{
    const int batch = blockIdx.z;
    const int j0 = blockIdx.y * 64, d0 = blockIdx.x * 64;
    __shared__ float Es[16][64], As[16][64];
    const unsigned short* Ep = (const unsigned short*)E + (size_t)batch * LA_ * LB_;
    const float* ap = a + (size_t)batch * LA_ * H_;
    const int t  = threadIdx.x;
    const int ki = t >> 4,  j4 = (t & 15) * 4;  // E staging: k row (i), col (j)
    const int ar = t >> 4,  ac = (t & 15) * 4;  // a staging: row (i=k), col (d)
    const int ty = t >> 4, tx = t & 15;
    float acc[4][4] = {};

    for (int k0 = 0; k0 < LA_; k0 += 16) {
        ushort4 ev = *(const ushort4*)(Ep + (size_t)(k0 + ki) * LB_ + j0 + j4);
        float4  av = *(const float4*)(ap + (size_t)(k0 + ar) * H_ + d0 + ac);
        __syncthreads();
        Es[ki][j4 + 0] = __bfloat162float(*(bf16*)&ev.x);
        Es[ki][j4 + 1] = __bfloat162float(*(bf16*)&ev.y);
        Es[ki][j4 + 2] = __bfloat162float(*(bf16*)&ev.z);
        Es[ki][j4 + 3] = __bfloat162float(*(bf16*)&ev.w);
        *(float4*)&As[ar][ac] = av;
        __syncthreads();
#pragma unroll
        for (int k = 0; k < 16; k++) {
            float4 am = *(const float4*)&Es[k][ty * 4];
            float4 an = *(const float4*)&As[k][tx * 4];
            float amv[4] = {am.x, am.y, am.z, am.w};
            float anv[4] = {an.x, an.y, an.z, an.w};
#pragma unroll
            for (int u = 0; u < 4; u++)
#pragma unroll
                for (int v = 0; v < 4; v++) acc[u][v] += amv[u] * anv[v];
        }
    }

    const int na = nA[batch];
#pragma unroll
    for (int u = 0; u < 4; u++) {
        const int j = j0 + ty * 4 + u;
        const int valid = mask_b[batch * LB_ + j] && (na > 0);
        const float inv = valid ? 1.0f / l_col[batch * LB_ + j] : 0.0f;
#pragma unroll
        for (int v = 0; v < 4; v++) {
            const int d = d0 + tx * 4 + v;
            float val = valid ? acc[u][v] * inv : mean_a[batch * H_ + d];
            out[(size_t)NB_ * LA_ * H_ + (size_t)batch * LB_ * H_ + (size_t)j * H_ + d] = val;
        }
    }
}

// ---------------------------------------------------------------------------
extern "C" void kernel_launch(void* const* d_in, const int* in_sizes, int n_in,
                              void* d_out, int out_size, void* d_ws, size_t ws_size,
                              hipStream_t stream)
{
    const float* a      = (const float*)d_in[0];
    const float* b      = (const float*)d_in[1];
    const int*   mask_a = (const int*)d_in[2];
    const int*   mask_b = (const int*)d_in[3];
    const float* temp   = (const float*)d_in[4];
    float* out = (float*)d_out;

    // workspace layout
    char* ws = (char*)d_ws;
    bf16*  E      = (bf16*)ws;                                  // 16*1024*1024*2 = 33,554,432 B
    float* l_row  = (float*)(ws + 33554432);                    // 65,536 B
    float* l_col  = (float*)(ws + 33554432 + 65536);            // 65,536 B
    float* mean_a = (float*)(ws + 33554432 + 131072);           // 32,768 B
    float* mean_b = (float*)(ws + 33554432 + 163840);           // 32,768 B
    int*   nA     = (int*)  (ws + 33554432 + 196608);
    int*   nB     = (int*)  (ws + 33554432 + 196608 + 64);

    k_attn_exp<<<dim3(LB_ / 64, LA_ / 64, NB_), 256, 0, stream>>>(a, b, mask_a, mask_b, temp, E);
    k_rowsum<<<dim3(NB_ * LA_ / 4), 256, 0, stream>>>(E, l_row);
    k_colsum<<<dim3(NB_ * 16), 256, 0, stream>>>(E, l_col);
    k_mean<<<dim3(H_ / 256, NB_, 2), 256, 0, stream>>>(a, b, mean_a, mean_b);
    k_count<<<dim3(NB_), 256, 0, stream>>>(mask_a, mask_b, nA, nB);
    k_feat_a<<<dim3(H_ / 64, LA_ / 64, NB_), 256, 0, stream>>>(E, b, mask_a, nB, l_row, mean_b, out);
    k_feat_b<<<dim3(H_ / 64, LB_ / 64, NB_), 256, 0, stream>>>(E, a, mask_b, nA, l_col, mean_a, out);
}

// Round 2
// 295.381 us; speedup vs baseline: 2.7551x; 2.7551x over previous
//
#include <hip/hip_runtime.h>
#include <hip/hip_bf16.h>

#define NB_ 16      // batches
#define LA_ 1024
#define LB_ 1024
#define H_  512

typedef __attribute__((ext_vector_type(8))) short short8;   // 8 bf16 = 4 VGPRs
typedef __attribute__((ext_vector_type(4))) float f32x4;    // MFMA C/D

using bf16 = __hip_bfloat16;

__device__ __forceinline__ float bf2f(unsigned short u) {
    union { unsigned int i; float f; } c; c.i = ((unsigned)u) << 16; return c.f;
}
__device__ __forceinline__ unsigned short f2bf(float f) {
    bf16 h = __float2bfloat16(f);
    return *(unsigned short*)&h;
}

__device__ __forceinline__ void load_lds16(const void* g, void* l) {
    __builtin_amdgcn_global_load_lds(
        (const __attribute__((address_space(1))) void*)g,
        (__attribute__((address_space(3))) void*)l, 16, 0, 0);
}

// ---------------------------------------------------------------------------
// Shared MFMA GEMM core: C(128x128) = A(128xK) . B^T(128xK), bf16, fp32 acc.
// LDS tiles [128][32] bf16, rows 64 B; 16B chunks XOR-swizzled by (row>>1)&3
// so fragment ds_read_b128s spread across bank groups.
// 256 threads = 4 waves; wave (wr,wc) owns a 64x64 quadrant, 4x4 fragments.
// ---------------------------------------------------------------------------
__device__ __forceinline__ void gemm_core(
    const unsigned short* __restrict__ A, const unsigned short* __restrict__ B,
    int lda, int ldb, int K,
    unsigned short* ldsA, unsigned short* ldsB, f32x4 acc[4][4])
{
    const int t = threadIdx.x;
    const int wave = t >> 6, lane = t & 63;
    const int wr = wave >> 1, wc = wave & 1;
    const int lm = lane & 15, q = lane >> 4;

    // fragment LDS read addresses (constant across K loop)
    const short8* ap[4]; const short8* bp[4];
#pragma unroll
    for (int f = 0; f < 4; f++) {
        const int ra = wr * 64 + f * 16 + lm;
        ap[f] = (const short8*)((const char*)ldsA + ra * 64 + ((q ^ ((ra >> 1) & 3)) << 4));
        const int rb = wc * 64 + f * 16 + lm;
        bp[f] = (const short8*)((const char*)ldsB + rb * 64 + ((q ^ ((rb >> 1) & 3)) << 4));
    }

    // staging: pass p covers rows p*64 + wave*16 + (lane>>2); lane&3 = physical
    // 16B chunk; global src chunk = physical ^ swizzle(row)
    const int srow0 = wave * 16 + (lane >> 2);
    const int pc = lane & 3;
    const int r0 = srow0,      c0 = pc ^ ((r0 >> 1) & 3);
    const int r1 = 64 + srow0, c1 = pc ^ ((r1 >> 1) & 3);
    const unsigned short* ga0 = A + (size_t)r0 * lda + c0 * 8;
    const unsigned short* ga1 = A + (size_t)r1 * lda + c1 * 8;
    const unsigned short* gb0 = B + (size_t)r0 * ldb + c0 * 8;
    const unsigned short* gb1 = B + (size_t)r1 * ldb + c1 * 8;
    char* la = (char*)ldsA + wave * 1024;   // wave-uniform LDS dst
    char* lb = (char*)ldsB + wave * 1024;

    for (int k0 = 0; k0 < K; k0 += 32) {
        __syncthreads();                    // protect LDS from prev-iter reads
        load_lds16(ga0 + k0, la);
        load_lds16(ga1 + k0, la + 4096);
        load_lds16(gb0 + k0, lb);
        load_lds16(gb1 + k0, lb + 4096);
        __syncthreads();                    // drains vmcnt before reads
        short8 av[4];
#pragma unroll
        for (int fm = 0; fm < 4; fm++) av[fm] = *ap[fm];
#pragma unroll
        for (int fn = 0; fn < 4; fn++) {
            const short8 bv = *bp[fn];
#pragma unroll
            for (int fm = 0; fm < 4; fm++)
                acc[fm][fn] = __builtin_amdgcn_mfma_f32_16x16x32_bf16(
                    av[fm], bv, acc[fm][fn], 0, 0, 0);
        }
    }
}

// ---------------------------------------------------------------------------
// GEMM1: S = a.b^T * temp; E = mask ? exp(S) : 0. Writes E and E^T (bf16).
// ---------------------------------------------------------------------------
__global__ __launch_bounds__(256) void k_gemm_attn(
    const unsigned short* __restrict__ a_bf, const unsigned short* __restrict__ b_bf,
    const int* __restrict__ mask_a, const int* __restrict__ mask_b,
    const float* __restrict__ temp_p,
    unsigned short* __restrict__ E, unsigned short* __restrict__ ET)
{
    __shared__ unsigned short ldsA[128 * 32], ldsB[128 * 32];
    const int batch = blockIdx.z;
    const int i0 = blockIdx.y * 128, j0 = blockIdx.x * 128;
    const unsigned short* A = a_bf + (size_t)batch * LA_ * H_ + (size_t)i0 * H_;
    const unsigned short* B = b_bf + (size_t)batch * LB_ * H_ + (size_t)j0 * H_;
    f32x4 acc[4][4];
#pragma unroll
    for (int x = 0; x < 4; x++)
#pragma unroll
        for (int y = 0; y < 4; y++) acc[x][y] = 0;

    gemm_core(A, B, H_, H_, H_, ldsA, ldsB, acc);

    const float temp = temp_p[0];
    const int t = threadIdx.x, wave = t >> 6, lane = t & 63;
    const int wr = wave >> 1, wc = wave & 1, lm = lane & 15, q = lane >> 4;
    const int* map = mask_a + batch * LA_;
    const int* mbp = mask_b + batch * LB_;
    unsigned short* Ep = E + (size_t)batch * LA_ * LB_;
    unsigned short* ETp = ET + (size_t)batch * LB_ * LA_;

    int mb[4];
#pragma unroll
    for (int fn = 0; fn < 4; fn++) mb[fn] = mbp[j0 + wc * 64 + fn * 16 + lm];

#pragma unroll
    for (int fm = 0; fm < 4; fm++) {
        const int ib = i0 + wr * 64 + fm * 16 + q * 4;
        int ma[4];
#pragma unroll
        for (int r = 0; r < 4; r++) ma[r] = map[ib + r];
#pragma unroll
        for (int fn = 0; fn < 4; fn++) {
            const int j = j0 + wc * 64 + fn * 16 + lm;
            ushort4 pk;
            unsigned short* pp = (unsigned short*)&pk;
#pragma unroll
            for (int r = 0; r < 4; r++) {
                const float e = (ma[r] && mb[fn]) ? __expf(acc[fm][fn][r] * temp) : 0.0f;
                const unsigned short u = f2bf(e);
                Ep[(size_t)(ib + r) * LB_ + j] = u;   // E: 2B scatter, merges in L2
                pp[r] = u;
            }
            *(ushort4*)(ETp + (size_t)j * LA_ + ib) = pk;  // ET: packed 8B
        }
    }
}

// ---------------------------------------------------------------------------
// GEMM2/3 shared: out = rownorm( Amat(1024x1024) . BT(512x1024)^T )
// with per-row validity fallback to meanv.
// ---------------------------------------------------------------------------
__global__ __launch_bounds__(256) void k_gemm_feat(
    const unsigned short* __restrict__ Amat,  // per-batch [1024][1024] bf16
    const unsigned short* __restrict__ BT,    // per-batch [512][1024] bf16
    const int* __restrict__ mask,             // per-batch [1024]
    const int* __restrict__ n_other,          // [NB]
    const float* __restrict__ sums,           // per-batch [1024]
    const float* __restrict__ meanv,          // per-batch [512]
    float* __restrict__ outb)                 // [NB][1024][512]
{
    __shared__ unsigned short ldsA[128 * 32], ldsB[128 * 32];
    const int batch = blockIdx.z;
    const int m0 = blockIdx.y * 128, n0 = blockIdx.x * 128;
    const unsigned short* A = Amat + (size_t)batch * 1024 * 1024 + (size_t)m0 * 1024;
    const unsigned short* B = BT + (size_t)batch * H_ * 1024 + (size_t)n0 * 1024;
    f32x4 acc[4][4];
#pragma unroll
    for (int x = 0; x < 4; x++)
#pragma unroll
        for (int y = 0; y < 4; y++) acc[x][y] = 0;

    gemm_core(A, B, 1024, 1024, 1024, ldsA, ldsB, acc);

    const int t = threadIdx.x, wave = t >> 6, lane = t & 63;
    const int wr = wave >> 1, wc = wave & 1, lm = lane & 15, q = lane >> 4;
    const int nn = n_other[batch];
    const int* mp = mask + batch * 1024;
    const float* sp = sums + batch * 1024;
    const float* mv = meanv + batch * H_;
    float* op = outb + (size_t)batch * 1024 * H_;

    float mval[4];
#pragma unroll
    for (int fn = 0; fn < 4; fn++) mval[fn] = mv[n0 + wc * 64 + fn * 16 + lm];

#pragma unroll
    for (int fm = 0; fm < 4; fm++) {
        const int ib = m0 + wr * 64 + fm * 16 + q * 4;
#pragma unroll
        for (int r = 0; r < 4; r++) {
            const int i = ib + r;
            const bool valid = (mp[i] != 0) && (nn > 0);
            const float inv = valid ? 1.0f / sp[i] : 0.0f;
#pragma unroll
            for (int fn = 0; fn < 4; fn++) {
                const int d = n0 + wc * 64 + fn * 16 + lm;
                op[(size_t)i * H_ + d] = valid ? acc[fm][fn][r] * inv : mval[fn];
            }
        }
    }
}

// ---------------------------------------------------------------------------
// prep: fp32 [1024][512] -> bf16 normal [1024][512] + transposed [512][1024]
// ---------------------------------------------------------------------------
__global__ __launch_bounds__(256) void k_prep(
    const float* __restrict__ src, unsigned short* __restrict__ dstN,
    unsigned short* __restrict__ dstT)
{
    __shared__ unsigned short lds[64][68];
    const int batch = blockIdx.z;
    const int d0 = blockIdx.x * 64, i0 = blockIdx.y * 64;
    const float* sp = src + (size_t)batch * 1024 * H_;
    unsigned short* np = dstN + (size_t)batch * 1024 * H_;
    unsigned short* tp = dstT + (size_t)batch * H_ * 1024;
    const int t = threadIdx.x;
    const int c4 = (t & 15) * 4;
#pragma unroll
    for (int it = 0; it < 4; it++) {
        const int r = (t >> 4) + it * 16;
        float4 v = *(const float4*)(sp + (size_t)(i0 + r) * H_ + d0 + c4);
        ushort4 u = make_ushort4(f2bf(v.x), f2bf(v.y), f2bf(v.z), f2bf(v.w));
        *(ushort4*)(np + (size_t)(i0 + r) * H_ + d0 + c4) = u;
        *(ushort4*)&lds[r][c4] = u;
    }
    __syncthreads();
#pragma unroll
    for (int it = 0; it < 4; it++) {
        const int dd = (t >> 4) + it * 16;
        const int i4 = (t & 15) * 4;
        ushort4 u = make_ushort4(lds[i4][dd], lds[i4 + 1][dd], lds[i4 + 2][dd], lds[i4 + 3][dd]);
        *(ushort4*)(tp + (size_t)(d0 + dd) * 1024 + i0 + i4) = u;
    }
}

// ---------------------------------------------------------------------------
// row sums of a bf16 [rows][1024] matrix; one wave per row
// ---------------------------------------------------------------------------
__global__ __launch_bounds__(256) void k_rowsum(const unsigned short* __restrict__ E,
                                                float* __restrict__ out)
{
    const int w = threadIdx.x >> 6, lane = threadIdx.x & 63;
    const int row = blockIdx.x * 4 + w;
    const unsigned short* p = E + (size_t)row * 1024;
    float s = 0.0f;
#pragma unroll
    for (int it = 0; it < 4; it++) {
        ushort4 u = *(const ushort4*)(p + it * 256 + (lane << 2));
        s += bf2f(u.x) + bf2f(u.y) + bf2f(u.z) + bf2f(u.w);
    }
    for (int off = 32; off; off >>= 1) s += __shfl_down(s, off, 64);
    if (lane == 0) out[row] = s;
}

// ---------------------------------------------------------------------------
// per-batch column means of a and b (fallback for fully-masked rows)
// ---------------------------------------------------------------------------
__global__ __launch_bounds__(256) void k_mean(const float* __restrict__ a,
                                              const float* __restrict__ b,
                                              float* __restrict__ mean_a,
                                              float* __restrict__ mean_b)
{
    const int d = blockIdx.x * 256 + threadIdx.x;
    const int batch = blockIdx.y;
    const float* src = (blockIdx.z == 0) ? a : b;
    float* dst = (blockIdx.z == 0) ? mean_a : mean_b;
    const float* p = src + (size_t)batch * 1024 * H_ + d;
    float s = 0.0f;
    for (int i = 0; i < 1024; i++) s += p[(size_t)i * H_];
    dst[batch * H_ + d] = s * (1.0f / 1024.0f);
}

// ---------------------------------------------------------------------------
// mask token counts per batch
// ---------------------------------------------------------------------------
__global__ __launch_bounds__(256) void k_count(const int* __restrict__ mask_a,
                                               const int* __restrict__ mask_b,
                                               int* __restrict__ nA, int* __restrict__ nB)
{
    const int batch = blockIdx.x, t = threadIdx.x;
    int sa = 0, sb = 0;
    for (int i = t; i < 1024; i += 256) {
        sa += mask_a[batch * 1024 + i];
        sb += mask_b[batch * 1024 + i];
    }
    __shared__ int ra[256], rb[256];
    ra[t] = sa; rb[t] = sb;
    __syncthreads();
    for (int off = 128; off; off >>= 1) {
        if (t < off) { ra[t] += ra[t + off]; rb[t] += rb[t + off]; }
        __syncthreads();
    }
    if (t == 0) { nA[batch] = ra[0]; nB[batch] = rb[0]; }
}

// ---------------------------------------------------------------------------
extern "C" void kernel_launch(void* const* d_in, const int* in_sizes, int n_in,
                              void* d_out, int out_size, void* d_ws, size_t ws_size,
                              hipStream_t stream)
{
    const float* a      = (const float*)d_in[0];
    const float* b      = (const float*)d_in[1];
    const int*   mask_a = (const int*)d_in[2];
    const int*   mask_b = (const int*)d_in[3];
    const float* temp   = (const float*)d_in[4];
    float* out = (float*)d_out;

    // workspace layout (~128.2 MiB)
    char* ws = (char*)d_ws;
    size_t off = 0;
    unsigned short* E    = (unsigned short*)(ws + off); off += (size_t)NB_ * LA_ * LB_ * 2;  // 32 MiB
    unsigned short* ET   = (unsigned short*)(ws + off); off += (size_t)NB_ * LB_ * LA_ * 2;  // 32 MiB
    unsigned short* a_bf = (unsigned short*)(ws + off); off += (size_t)NB_ * LA_ * H_ * 2;   // 16 MiB
    unsigned short* b_bf = (unsigned short*)(ws + off); off += (size_t)NB_ * LB_ * H_ * 2;   // 16 MiB
    unsigned short* aT   = (unsigned short*)(ws + off); off += (size_t)NB_ * H_ * LA_ * 2;   // 16 MiB
    unsigned short* bT   = (unsigned short*)(ws + off); off += (size_t)NB_ * H_ * LB_ * 2;   // 16 MiB
    float* l_row  = (float*)(ws + off); off += (size_t)NB_ * LA_ * 4;
    float* l_col  = (float*)(ws + off); off += (size_t)NB_ * LB_ * 4;
    float* mean_a = (float*)(ws + off); off += (size_t)NB_ * H_ * 4;
    float* mean_b = (float*)(ws + off); off += (size_t)NB_ * H_ * 4;
    int*   nA     = (int*)(ws + off); off += 64;
    int*   nB     = (int*)(ws + off); off += 64;

    k_prep<<<dim3(H_ / 64, 1024 / 64, NB_), 256, 0, stream>>>(a, a_bf, aT);
    k_prep<<<dim3(H_ / 64, 1024 / 64, NB_), 256, 0, stream>>>(b, b_bf, bT);
    k_mean<<<dim3(H_ / 256, NB_, 2), 256, 0, stream>>>(a, b, mean_a, mean_b);
    k_count<<<dim3(NB_), 256, 0, stream>>>(mask_a, mask_b, nA, nB);

    k_gemm_attn<<<dim3(LB_ / 128, LA_ / 128, NB_), 256, 0, stream>>>(
        a_bf, b_bf, mask_a, mask_b, temp, E, ET);

    k_rowsum<<<dim3(NB_ * LA_ / 4), 256, 0, stream>>>(E, l_row);
    k_rowsum<<<dim3(NB_ * LB_ / 4), 256, 0, stream>>>(ET, l_col);

    k_gemm_feat<<<dim3(H_ / 128, LA_ / 128, NB_), 256, 0, stream>>>(
        E, bT, mask_a, nB, l_row, mean_b, out);
    k_gemm_feat<<<dim3(H_ / 128, LB_ / 128, NB_), 256, 0, stream>>>(
        ET, aT, mask_b, nA, l_col, mean_a, out + (size_t)NB_ * LA_ * H_);
}

// Round 3
// 245.643 us; speedup vs baseline: 3.3130x; 1.2025x over previous
//
#include <hip/hip_runtime.h>
#include <hip/hip_bf16.h>

#define NB_ 16      // batches
#define LA_ 1024
#define LB_ 1024
#define H_  512

typedef __attribute__((ext_vector_type(8))) short short8;   // 8 bf16 = 4 VGPRs
typedef __attribute__((ext_vector_type(4))) float f32x4;    // MFMA C/D

using bf16 = __hip_bfloat16;

__device__ __forceinline__ float bf2f(unsigned short u) {
    union { unsigned int i; float f; } c; c.i = ((unsigned)u) << 16; return c.f;
}
__device__ __forceinline__ unsigned short f2bf(float f) {
    bf16 h = __float2bfloat16(f);
    return *(unsigned short*)&h;
}

__device__ __forceinline__ void load_lds16(const void* g, void* l) {
    __builtin_amdgcn_global_load_lds(
        (const __attribute__((address_space(1))) void*)g,
        (__attribute__((address_space(3))) void*)l, 16, 0, 0);
}

// ---------------------------------------------------------------------------
// MFMA GEMM core, BK=64: C(128x128) = A(128xK) . B^T(128xK), bf16, fp32 acc.
// LDS tiles [128][64] bf16 (128 B rows = 8 x 16B chunks); chunk XOR-swizzled
// by (row&7). 32 MFMA + 8 global_load_lds per barrier pair (half the vmcnt(0)
// drains of BK=32). 4 waves, 64x64 quadrant each, 4x4 fragments.
// ---------------------------------------------------------------------------
__device__ __forceinline__ void gemm_core64(
    const unsigned short* __restrict__ A, const unsigned short* __restrict__ B,
    int lda, int ldb, int K,
    unsigned short* ldsA, unsigned short* ldsB, f32x4 acc[4][4])
{
    const int t = threadIdx.x;
    const int wave = t >> 6, lane = t & 63;
    const int wr = wave >> 1, wc = wave & 1;
    const int lm = lane & 15, q = lane >> 4;

    // fragment LDS byte offsets for kk=0; kk=1 is addr ^ 64 (chunk bit2 flip)
    int aoff[4], boff[4];
#pragma unroll
    for (int f = 0; f < 4; f++) {
        const int ra = wr * 64 + f * 16 + lm;
        aoff[f] = ra * 128 + ((q ^ (ra & 7)) << 4);
        const int rb = wc * 64 + f * 16 + lm;
        boff[f] = rb * 128 + ((q ^ (rb & 7)) << 4);
    }

    // staging: instr s covers rows (s*4+wave)*8 .. +7; lane = r8*8 + c;
    // LDS slot chunk c holds global chunk c ^ (row&7); row&7 is s-invariant.
    const int row0 = wave * 8 + (lane >> 3);
    const int sc = (lane & 7) ^ (row0 & 7);
    const unsigned short* gA0 = A + (size_t)row0 * lda + sc * 8;
    const unsigned short* gB0 = B + (size_t)row0 * ldb + sc * 8;
    const int sA = 32 * lda, sB = 32 * ldb;      // shorts per s-step
    char* lA = (char*)ldsA + wave * 1024;        // wave-uniform LDS dst
    char* lB = (char*)ldsB + wave * 1024;

    for (int k0 = 0; k0 < K; k0 += 64) {
        __syncthreads();                         // protect LDS from prev-iter reads
#pragma unroll
        for (int s = 0; s < 4; s++) {
            load_lds16(gA0 + k0 + s * sA, lA + s * 4096);
            load_lds16(gB0 + k0 + s * sB, lB + s * 4096);
        }
        __syncthreads();                         // drains vmcnt before reads
#pragma unroll
        for (int kk = 0; kk < 2; kk++) {
            const int kx = kk << 6;
            short8 av[4];
#pragma unroll
            for (int fm = 0; fm < 4; fm++)
                av[fm] = *(const short8*)((const char*)ldsA + (aoff[fm] ^ kx));
#pragma unroll
            for (int fn = 0; fn < 4; fn++) {
                const short8 bv = *(const short8*)((const char*)ldsB + (boff[fn] ^ kx));
#pragma unroll
                for (int fm = 0; fm < 4; fm++)
                    acc[fm][fn] = __builtin_amdgcn_mfma_f32_16x16x32_bf16(
                        av[fm], bv, acc[fm][fn], 0, 0, 0);
            }
        }
    }
}

// ---------------------------------------------------------------------------
// GEMM1: S = a.b^T * temp; E = mask ? exp(S) : 0. Writes packed E (via LDS
// transpose) and packed ET (from regs), plus atomic l_row / l_col partials.
// ---------------------------------------------------------------------------
__global__ __launch_bounds__(256) void k_gemm_attn(
    const unsigned short* __restrict__ a_bf, const unsigned short* __restrict__ b_bf,
    const int* __restrict__ mask_a, const int* __restrict__ mask_b,
    const float* __restrict__ temp_p,
    unsigned short* __restrict__ E, unsigned short* __restrict__ ET,
    float* __restrict__ l_row, float* __restrict__ l_col)
{
    __shared__ unsigned short lds[16384];        // 32 KB: staging, then E tile
    unsigned short* ldsA = lds;
    unsigned short* ldsB = lds + 8192;

    const int batch = blockIdx.z;
    const int i0 = blockIdx.y * 128, j0 = blockIdx.x * 128;
    const unsigned short* A = a_bf + (size_t)batch * LA_ * H_ + (size_t)i0 * H_;
    const unsigned short* B = b_bf + (size_t)batch * LB_ * H_ + (size_t)j0 * H_;
    f32x4 acc[4][4];
#pragma unroll
    for (int x = 0; x < 4; x++)
#pragma unroll
        for (int y = 0; y < 4; y++) acc[x][y] = 0;

    gemm_core64(A, B, H_, H_, H_, ldsA, ldsB, acc);

    const float temp = temp_p[0];
    const int t = threadIdx.x, wave = t >> 6, lane = t & 63;
    const int wr = wave >> 1, wc = wave & 1, lm = lane & 15, q = lane >> 4;
    const int* map = mask_a + batch * LA_;
    const int* mbp = mask_b + batch * LB_;
    unsigned short* Ep  = E  + (size_t)batch * LA_ * LB_;
    unsigned short* ETp = ET + (size_t)batch * LB_ * LA_;
    float* lrp = l_row + batch * LA_;
    float* lcp = l_col + batch * LB_;

    int mb[4];
#pragma unroll
    for (int fn = 0; fn < 4; fn++) mb[fn] = mbp[j0 + wc * 64 + fn * 16 + lm];

    // transform acc -> e (in place) and store packed ET rows from regs
#pragma unroll
    for (int fm = 0; fm < 4; fm++) {
        const int ib = i0 + wr * 64 + fm * 16 + q * 4;
        int ma[4];
#pragma unroll
        for (int r = 0; r < 4; r++) ma[r] = map[ib + r];
#pragma unroll
        for (int fn = 0; fn < 4; fn++) {
            const int j = j0 + wc * 64 + fn * 16 + lm;
            ushort4 pk;
            unsigned short* pp = (unsigned short*)&pk;
#pragma unroll
            for (int r = 0; r < 4; r++) {
                const float e = (ma[r] && mb[fn]) ? __expf(acc[fm][fn][r] * temp) : 0.0f;
                acc[fm][fn][r] = e;
                pp[r] = f2bf(e);
            }
            *(ushort4*)(ETp + (size_t)j * LA_ + ib) = pk;
        }
    }

    // l_row partials: sum over this block's 128 j's
#pragma unroll
    for (int fm = 0; fm < 4; fm++)
#pragma unroll
        for (int r = 0; r < 4; r++) {
            float s = acc[fm][0][r] + acc[fm][1][r] + acc[fm][2][r] + acc[fm][3][r];
            s += __shfl_xor(s, 1, 16); s += __shfl_xor(s, 2, 16);
            s += __shfl_xor(s, 4, 16); s += __shfl_xor(s, 8, 16);
            if (lm == 0) atomicAdd(&lrp[i0 + wr * 64 + fm * 16 + q * 4 + r], s);
        }
    // l_col partials: sum over this block's 128 i's
#pragma unroll
    for (int fn = 0; fn < 4; fn++) {
        float s = 0.0f;
#pragma unroll
        for (int fm = 0; fm < 4; fm++)
#pragma unroll
            for (int r = 0; r < 4; r++) s += acc[fm][fn][r];
        s += __shfl_xor(s, 16, 64); s += __shfl_xor(s, 32, 64);
        if (lane < 16) atomicAdd(&lcp[j0 + wc * 64 + fn * 16 + lm], s);
    }

    // packed E via swizzled LDS transpose (reuse staging LDS)
    __syncthreads();
#pragma unroll
    for (int fm = 0; fm < 4; fm++)
#pragma unroll
        for (int fn = 0; fn < 4; fn++)
#pragma unroll
            for (int r = 0; r < 4; r++) {
                const int il = wr * 64 + fm * 16 + q * 4 + r;
                const int jl = wc * 64 + fn * 16 + lm;
                lds[il * 128 + (((jl >> 3) ^ ((il >> 1) & 7)) << 3) + (jl & 7)] =
                    f2bf(acc[fm][fn][r]);
            }
    __syncthreads();
#pragma unroll
    for (int rep = 0; rep < 8; rep++) {
        const int il = (t >> 4) + rep * 16;
        const int jc = t & 15;
        const int phys = jc ^ ((il >> 1) & 7);
        short8 v = *(const short8*)(lds + il * 128 + phys * 8);
        *(short8*)(Ep + (size_t)(i0 + il) * LB_ + j0 + jc * 8) = v;
    }
}

// ---------------------------------------------------------------------------
// GEMM2+3 merged: z<16 -> feature_a (E . bT^T), z>=16 -> feature_b (ET . aT^T)
// out = rownorm(Amat . Bm^T) with fallback to meanv for invalid rows.
// ---------------------------------------------------------------------------
__global__ __launch_bounds__(256) void k_gemm_feat(
    const unsigned short* __restrict__ E, const unsigned short* __restrict__ ET,
    const unsigned short* __restrict__ aT, const unsigned short* __restrict__ bT,
    const int* __restrict__ mask_a, const int* __restrict__ mask_b,
    const int* __restrict__ nA, const int* __restrict__ nB,
    const float* __restrict__ l_row, const float* __restrict__ l_col,
    const float* __restrict__ mean_a, const float* __restrict__ mean_b,
    float* __restrict__ out)
{
    __shared__ unsigned short lds[16384];
    unsigned short* ldsA = lds;
    unsigned short* ldsB = lds + 8192;

    const int z = blockIdx.z;
    const int batch = z & 15;
    const bool isA = z < 16;
    const unsigned short* Amat = (isA ? E : ET) + (size_t)batch * 1024 * 1024;
    const unsigned short* Bm   = (isA ? bT : aT) + (size_t)batch * H_ * 1024;
    const int* mp   = (isA ? mask_a : mask_b) + batch * 1024;
    const int nn    = (isA ? nB : nA)[batch];
    const float* sp = (isA ? l_row : l_col) + batch * 1024;
    const float* mv = (isA ? mean_b : mean_a) + batch * H_;
    float* op = out + (isA ? (size_t)0 : (size_t)NB_ * LA_ * H_) + (size_t)batch * 1024 * H_;

    const int m0 = blockIdx.y * 128, n0 = blockIdx.x * 128;
    f32x4 acc[4][4];
#pragma unroll
    for (int x = 0; x < 4; x++)
#pragma unroll
        for (int y = 0; y < 4; y++) acc[x][y] = 0;

    gemm_core64(Amat + (size_t)m0 * 1024, Bm + (size_t)n0 * 1024,
                1024, 1024, 1024, ldsA, ldsB, acc);

    const int t = threadIdx.x, wave = t >> 6, lane = t & 63;
    const int wr = wave >> 1, wc = wave & 1, lm = lane & 15, q = lane >> 4;

    float mval[4];
#pragma unroll
    for (int fn = 0; fn < 4; fn++) mval[fn] = mv[n0 + wc * 64 + fn * 16 + lm];

#pragma unroll
    for (int fm = 0; fm < 4; fm++) {
        const int ib = m0 + wr * 64 + fm * 16 + q * 4;
#pragma unroll
        for (int r = 0; r < 4; r++) {
            const int i = ib + r;
            const bool valid = (mp[i] != 0) && (nn > 0);
            const float inv = valid ? 1.0f / sp[i] : 0.0f;
#pragma unroll
            for (int fn = 0; fn < 4; fn++) {
                const int d = n0 + wc * 64 + fn * 16 + lm;
                op[(size_t)i * H_ + d] = valid ? acc[fm][fn][r] * inv : mval[fn];
            }
        }
    }
}

// ---------------------------------------------------------------------------
// prep (a and b merged): fp32 [1024][512] -> bf16 [1024][512] + bf16^T
// [512][1024], plus atomic per-batch column-mean partials.
// ---------------------------------------------------------------------------
__global__ __launch_bounds__(256) void k_prep(
    const float* __restrict__ a, const float* __restrict__ b,
    unsigned short* __restrict__ aN, unsigned short* __restrict__ bN,
    unsigned short* __restrict__ aT, unsigned short* __restrict__ bT,
    float* __restrict__ mean_a, float* __restrict__ mean_b)
{
    __shared__ unsigned short lds[64][68];
    __shared__ float smean[64];
    const int z = blockIdx.z;
    const int batch = z & 15, sel = z >> 4;
    const float* src = sel ? b : a;
    unsigned short* np = (sel ? bN : aN) + (size_t)batch * 1024 * H_;
    unsigned short* tp = (sel ? bT : aT) + (size_t)batch * H_ * 1024;
    float* mdst = (sel ? mean_b : mean_a) + batch * H_;
    const float* sp = src + (size_t)batch * 1024 * H_;

    const int d0 = blockIdx.x * 64, i0 = blockIdx.y * 64;
    const int t = threadIdx.x;
    if (t < 64) smean[t] = 0.0f;
    const int c4 = (t & 15) * 4;
#pragma unroll
    for (int it = 0; it < 4; it++) {
        const int r = (t >> 4) + it * 16;
        float4 v = *(const float4*)(sp + (size_t)(i0 + r) * H_ + d0 + c4);
        ushort4 u = make_ushort4(f2bf(v.x), f2bf(v.y), f2bf(v.z), f2bf(v.w));
        *(ushort4*)(np + (size_t)(i0 + r) * H_ + d0 + c4) = u;
        *(ushort4*)&lds[r][c4] = u;
    }
    __syncthreads();
#pragma unroll
    for (int it = 0; it < 4; it++) {
        const int dd = (t >> 4) + it * 16;
        const int i4 = (t & 15) * 4;
        ushort4 u = make_ushort4(lds[i4][dd], lds[i4 + 1][dd], lds[i4 + 2][dd], lds[i4 + 3][dd]);
        *(ushort4*)(tp + (size_t)(d0 + dd) * 1024 + i0 + i4) = u;
        atomicAdd(&smean[dd], bf2f(u.x) + bf2f(u.y) + bf2f(u.z) + bf2f(u.w));
    }
    __syncthreads();
    if (t < 64) atomicAdd(&mdst[d0 + t], smean[t] * (1.0f / 1024.0f));
}

// ---------------------------------------------------------------------------
// mask token counts per batch
// ---------------------------------------------------------------------------
__global__ __launch_bounds__(256) void k_count(const int* __restrict__ mask_a,
                                               const int* __restrict__ mask_b,
                                               int* __restrict__ nA, int* __restrict__ nB)
{
    const int batch = blockIdx.x, t = threadIdx.x;
    int sa = 0, sb = 0;
    for (int i = t; i < 1024; i += 256) {
        sa += mask_a[batch * 1024 + i];
        sb += mask_b[batch * 1024 + i];
    }
    __shared__ int ra[256], rb[256];
    ra[t] = sa; rb[t] = sb;
    __syncthreads();
    for (int off = 128; off; off >>= 1) {
        if (t < off) { ra[t] += ra[t + off]; rb[t] += rb[t + off]; }
        __syncthreads();
    }
    if (t == 0) { nA[batch] = ra[0]; nB[batch] = rb[0]; }
}

// ---------------------------------------------------------------------------
extern "C" void kernel_launch(void* const* d_in, const int* in_sizes, int n_in,
                              void* d_out, int out_size, void* d_ws, size_t ws_size,
                              hipStream_t stream)
{
    const float* a      = (const float*)d_in[0];
    const float* b      = (const float*)d_in[1];
    const int*   mask_a = (const int*)d_in[2];
    const int*   mask_b = (const int*)d_in[3];
    const float* temp   = (const float*)d_in[4];
    float* out = (float*)d_out;

    // workspace layout (~128.2 MiB)
    char* ws = (char*)d_ws;
    size_t off = 0;
    unsigned short* E    = (unsigned short*)(ws + off); off += (size_t)NB_ * LA_ * LB_ * 2;  // 32 MiB
    unsigned short* ET   = (unsigned short*)(ws + off); off += (size_t)NB_ * LB_ * LA_ * 2;  // 32 MiB
    unsigned short* a_bf = (unsigned short*)(ws + off); off += (size_t)NB_ * LA_ * H_ * 2;   // 16 MiB
    unsigned short* b_bf = (unsigned short*)(ws + off); off += (size_t)NB_ * LB_ * H_ * 2;   // 16 MiB
    unsigned short* aT   = (unsigned short*)(ws + off); off += (size_t)NB_ * H_ * LA_ * 2;   // 16 MiB
    unsigned short* bT   = (unsigned short*)(ws + off); off += (size_t)NB_ * H_ * LB_ * 2;   // 16 MiB
    float* l_row  = (float*)(ws + off); off += (size_t)NB_ * LA_ * 4;   // zeroed region start
    float* l_col  = (float*)(ws + off); off += (size_t)NB_ * LB_ * 4;
    float* mean_a = (float*)(ws + off); off += (size_t)NB_ * H_ * 4;
    float* mean_b = (float*)(ws + off); off += (size_t)NB_ * H_ * 4;
    int*   nA     = (int*)(ws + off); off += 64;
    int*   nB     = (int*)(ws + off); off += 64;

    // zero the atomic accumulators (l_row, l_col, mean_a, mean_b contiguous)
    hipMemsetAsync(l_row, 0, (size_t)NB_ * (LA_ + LB_ + H_ + H_) * 4, stream);

    k_prep<<<dim3(H_ / 64, 1024 / 64, 32), 256, 0, stream>>>(
        a, b, a_bf, b_bf, aT, bT, mean_a, mean_b);
    k_count<<<dim3(NB_), 256, 0, stream>>>(mask_a, mask_b, nA, nB);

    k_gemm_attn<<<dim3(LB_ / 128, LA_ / 128, NB_), 256, 0, stream>>>(
        a_bf, b_bf, mask_a, mask_b, temp, E, ET, l_row, l_col);

    k_gemm_feat<<<dim3(H_ / 128, 1024 / 128, 32), 256, 0, stream>>>(
        E, ET, aT, bT, mask_a, mask_b, nA, nB, l_row, l_col, mean_a, mean_b, out);
}